// Round 7
// baseline (1228.239 us; speedup 1.0000x reference)
//
#include <hip/hip_runtime.h>
#include <stdint.h>

typedef __attribute__((ext_vector_type(8))) short short8;
typedef __attribute__((ext_vector_type(4))) short short4v;
typedef __attribute__((ext_vector_type(4))) float float4v;
typedef __attribute__((ext_vector_type(4))) unsigned int uint4v;

#define NSEQ   4096
#define DMODEL 1024
#define NHEAD  16
#define DK     64
#define NP     512
#define MTOT   4608
#define NCH    24
#define CH     192   // 4608 / 24, multiple of 32
#define SCALE  2.8284271247461903f   // 64^0.25

__device__ __forceinline__ float b2f(unsigned short u) {
  union { unsigned u; float f; } x; x.u = ((unsigned)u) << 16; return x.f;
}
__device__ __forceinline__ unsigned short f2b(float f) {
  union { float f; unsigned u; } x; x.f = f;
  unsigned r = x.u + 0x7fffu + ((x.u >> 16) & 1u);
  return (unsigned short)(r >> 16);
}
__device__ __forceinline__ void split1(float x, unsigned short& h, unsigned short& l) {
  h = f2b(x);
  l = f2b(x - b2f(h));
}
__device__ __forceinline__ void gload16(const void* g, void* l) {
  __builtin_amdgcn_global_load_lds((const __attribute__((address_space(1))) void*)g,
                                   (__attribute__((address_space(3))) void*)l,
                                   16, 0, 0);
}
// 16B fragment from an 8B-aligned LDS address (stride-18-u32 rows): two b64 reads.
__device__ __forceinline__ short8 ld8(const unsigned* p) {
  union { short8 s; short4v h[2]; } u;
  u.h[0] = *(const short4v*)p;
  u.h[1] = *(const short4v*)(p + 2);
  return u.s;
}

// XCD-aware swizzle: lin%8 = hw XCD (round-robin); each XCD covers 16
// contiguous row-strips, col fastest -> A strip fetched once per XCD L2.
__device__ __forceinline__ void swz(int lin, long& brow, long& bcol) {
  brow = (long)(((lin & 7) << 4) | (lin >> 6)) * 128;
  bcol = (long)((lin >> 3) & 7) * 128;
}

__device__ __forceinline__ void split8_store(const float4v& x0, const float4v& x1,
                                             unsigned short* hi, unsigned short* lo, int i) {
  unsigned short h[8], l[8];
#pragma unroll
  for (int j = 0; j < 4; ++j) split1(x0[j], h[j], l[j]);
#pragma unroll
  for (int j = 0; j < 4; ++j) split1(x1[j], h[4 + j], l[4 + j]);
  uint4v ph, pl;
#pragma unroll
  for (int j = 0; j < 4; ++j) {
    ph[j] = (unsigned)h[2 * j] | ((unsigned)h[2 * j + 1] << 16);
    pl[j] = (unsigned)l[2 * j] | ((unsigned)l[2 * j + 1] << 16);
  }
  *(uint4v*)(hi + i) = ph;
  *(uint4v*)(lo + i) = pl;
}

// ---------------- merged: K input hi/lo split (blocks 0..8191) + all four
// weight hi/lo splits (blocks 8192..10239; 512 blocks per weight).
__global__ __launch_bounds__(256) void cvt_kw(const float* __restrict__ Kin,
                                              unsigned short* __restrict__ Khi,
                                              unsigned short* __restrict__ Klo,
                                              const float* __restrict__ w0,
                                              const float* __restrict__ w1,
                                              const float* __restrict__ w2,
                                              const float* __restrict__ w3,
                                              unsigned short* __restrict__ hibase) {
  const int bid = blockIdx.x;
  if (bid < 8192) {
    const int i = (bid * 256 + threadIdx.x) * 8;
    float4v x0 = *(const float4v*)(Kin + i);
    float4v x1 = *(const float4v*)(Kin + i + 4);
    split8_store(x0, x1, Khi, Klo, i);
  } else {
    const int wb = bid - 8192;
    const int y = wb >> 9;
    const float* s = (y == 0) ? w0 : (y == 1) ? w1 : (y == 2) ? w2 : w3;
    unsigned short* hi = hibase + (long)y * 2097152;
    unsigned short* lo = hi + 1048576;
    const int i = ((wb & 511) * 256 + threadIdx.x) * 8;
    float4v x0 = *(const float4v*)(s + i);
    float4v x1 = *(const float4v*)(s + i + 4);
    split8_store(x0, x1, hi, lo, i);
  }
}

// ---------------- f32 -> bf16 hi only (V input)
__global__ __launch_bounds__(256) void cvt_hi(const float* __restrict__ s,
                                              unsigned short* __restrict__ hi, int n) {
  const int i = (blockIdx.x * 256 + threadIdx.x) * 8;
  if (i + 8 > n) return;
  float4v x0 = *(const float4v*)(s + i);
  float4v x1 = *(const float4v*)(s + i + 4);
  uint4v ph;
  ph[0] = (unsigned)f2b(x0[0]) | ((unsigned)f2b(x0[1]) << 16);
  ph[1] = (unsigned)f2b(x0[2]) | ((unsigned)f2b(x0[3]) << 16);
  ph[2] = (unsigned)f2b(x1[0]) | ((unsigned)f2b(x1[1]) << 16);
  ph[3] = (unsigned)f2b(x1[2]) | ((unsigned)f2b(x1[3]) << 16);
  *(uint4v*)(hi + i) = ph;
}

// ---------------- merged: Q input -> bf16 hi (blocks 0..8191) + reduce_kv2
// (blocks 8192..9215): reduce chunk kv + Z, normalize, write kvT[bh][e][d].
__global__ __launch_bounds__(256) void cvt_q_reduce(const float* __restrict__ Qin,
                                                    unsigned short* __restrict__ Qhi,
                                                    const float* __restrict__ pkv,
                                                    const float* __restrict__ pZ,
                                                    float* __restrict__ kvT) {
  const int bid = blockIdx.x;
  if (bid < 8192) {
    const int i = (bid * 256 + threadIdx.x) * 8;
    float4v x0 = *(const float4v*)(Qin + i);
    float4v x1 = *(const float4v*)(Qin + i + 4);
    uint4v ph;
    ph[0] = (unsigned)f2b(x0[0]) | ((unsigned)f2b(x0[1]) << 16);
    ph[1] = (unsigned)f2b(x0[2]) | ((unsigned)f2b(x0[3]) << 16);
    ph[2] = (unsigned)f2b(x1[0]) | ((unsigned)f2b(x1[1]) << 16);
    ph[3] = (unsigned)f2b(x1[2]) | ((unsigned)f2b(x1[3]) << 16);
    *(uint4v*)(Qhi + i) = ph;
  } else {
    const int idx = (bid - 8192) * 256 + threadIdx.x;
    const int bh = idx >> 12, de = idx & 4095, d = de >> 6, e = de & 63;
    float s = 0.f;
#pragma unroll
    for (int c = 0; c < NCH; ++c) s += pkv[(((long)(bh * NCH + c)) << 12) + de];
    float Z = 0.f;
#pragma unroll
    for (int c = 0; c < NCH; ++c) Z += pZ[(bh * NCH + c) * 64 + d];
    kvT[((long)bh << 12) + e * 64 + d] = s / Z;
  }
}

// ---------------- pure-bf16 NT GEMM (m97 path): C[M,N] = A[M,K] @ B[N,K]^T.
template<int BF16OUT>
__global__ __launch_bounds__(256, 6) void gemm_bt(const unsigned short* __restrict__ A,
                                                  const unsigned short* __restrict__ B,
                                                  void* __restrict__ Cv,
                                                  int N, int K) {
  __shared__ unsigned short As[4096];
  __shared__ unsigned short Bs[4096];
  const int tid = threadIdx.x;
  const int w = tid >> 6, lane = tid & 63;
  const int wr = w >> 1, wc = w & 1;
  long brow, bcol; swz(blockIdx.x, brow, bcol);

  const int r0 = tid >> 2;
  const int kc = (tid & 3) * 8;
  const unsigned short* Ag0 = A + (brow + r0) * (long)K + kc;
  const unsigned short* Ag1 = Ag0 + 64L * K;
  const unsigned short* Bg0 = B + (bcol + r0) * (long)K + kc;
  const unsigned short* Bg1 = Bg0 + 64L * K;
  unsigned short* As0 = &As[w * 512];
  unsigned short* Bs0 = &Bs[w * 512];

  float4v acc[4][4];
#pragma unroll
  for (int i = 0; i < 4; ++i)
#pragma unroll
    for (int j = 0; j < 4; ++j) acc[i][j] = (float4v){0.f, 0.f, 0.f, 0.f};

  const int m15 = lane & 15, q8 = (lane >> 4) * 8;

  for (int k0 = 0; k0 < K; k0 += 32) {
    gload16(Ag0 + k0, As0);
    gload16(Ag1 + k0, As0 + 2048);
    gload16(Bg0 + k0, Bs0);
    gload16(Bg1 + k0, Bs0 + 2048);
    __syncthreads();
    short8 af[4], bfr[4];
#pragma unroll
    for (int t = 0; t < 4; ++t) {
      af[t]  = *(const short8*)&As[(wr * 64 + t * 16 + m15) * 32 + q8];
      bfr[t] = *(const short8*)&Bs[(wc * 64 + t * 16 + m15) * 32 + q8];
    }
#pragma unroll
    for (int mt = 0; mt < 4; ++mt)
#pragma unroll
      for (int nt = 0; nt < 4; ++nt)
        acc[mt][nt] = __builtin_amdgcn_mfma_f32_16x16x32_bf16(af[mt], bfr[nt], acc[mt][nt], 0, 0, 0);
    __syncthreads();
  }

  const long col  = bcol + wc * 64 + m15;
  const long rowb = brow + wr * 64 + (lane >> 4) * 4;
  if constexpr (BF16OUT) {
    unsigned short* C = (unsigned short*)Cv;
#pragma unroll
    for (int mt = 0; mt < 4; ++mt)
#pragma unroll
      for (int nt = 0; nt < 4; ++nt)
#pragma unroll
        for (int i = 0; i < 4; ++i)
          C[(rowb + mt * 16 + i) * (long)N + col + nt * 16] = f2b(acc[mt][nt][i]);
  } else {
    float* C = (float*)Cv;
#pragma unroll
    for (int mt = 0; mt < 4; ++mt)
#pragma unroll
      for (int nt = 0; nt < 4; ++nt)
#pragma unroll
        for (int i = 0; i < 4; ++i)
          C[(rowb + mt * 16 + i) * (long)N + col + nt * 16] = acc[mt][nt][i];
  }
}

// ---------------- 2-term split-bf16 NT GEMM (K projection), fused exp epilogue:
// k = Ah*Bh^T + Al*Bh^T (exact-A @ bf16-W); writes Eh/El = split(exp(k*SCALE)).
__global__ __launch_bounds__(256, 6) void gemm_2t_exp(const unsigned short* __restrict__ Ah,
                                                      const unsigned short* __restrict__ Al,
                                                      const unsigned short* __restrict__ Bh,
                                                      unsigned short* __restrict__ Eh,
                                                      unsigned short* __restrict__ El,
                                                      int N, int K) {
  __shared__ unsigned short Ash[4096];
  __shared__ unsigned short Asl[4096];
  __shared__ unsigned short Bsh[4096];
  const int tid = threadIdx.x;
  const int w = tid >> 6, lane = tid & 63;
  const int wr = w >> 1, wc = w & 1;
  long brow, bcol; swz(blockIdx.x, brow, bcol);

  const int r0 = tid >> 2;
  const int kc = (tid & 3) * 8;
  const unsigned short* Ahg0 = Ah + (brow + r0) * (long)K + kc;
  const unsigned short* Ahg1 = Ahg0 + 64L * K;
  const unsigned short* Alg0 = Al + (brow + r0) * (long)K + kc;
  const unsigned short* Alg1 = Alg0 + 64L * K;
  const unsigned short* Bhg0 = Bh + (bcol + r0) * (long)K + kc;
  const unsigned short* Bhg1 = Bhg0 + 64L * K;
  unsigned short* Ash0 = &Ash[w * 512];
  unsigned short* Asl0 = &Asl[w * 512];
  unsigned short* Bsh0 = &Bsh[w * 512];

  float4v acc[4][4];
#pragma unroll
  for (int i = 0; i < 4; ++i)
#pragma unroll
    for (int j = 0; j < 4; ++j) acc[i][j] = (float4v){0.f, 0.f, 0.f, 0.f};

  const int m15 = lane & 15, q8 = (lane >> 4) * 8;

  for (int k0 = 0; k0 < K; k0 += 32) {
    gload16(Ahg0 + k0, Ash0);
    gload16(Ahg1 + k0, Ash0 + 2048);
    gload16(Alg0 + k0, Asl0);
    gload16(Alg1 + k0, Asl0 + 2048);
    gload16(Bhg0 + k0, Bsh0);
    gload16(Bhg1 + k0, Bsh0 + 2048);
    __syncthreads();
    short8 ah[4], al[4], bh[4];
#pragma unroll
    for (int t = 0; t < 4; ++t) {
      const int ar = (wr * 64 + t * 16 + m15) * 32 + q8;
      const int br = (wc * 64 + t * 16 + m15) * 32 + q8;
      ah[t] = *(const short8*)&Ash[ar];
      al[t] = *(const short8*)&Asl[ar];
      bh[t] = *(const short8*)&Bsh[br];
    }
#pragma unroll
    for (int mt = 0; mt < 4; ++mt)
#pragma unroll
      for (int nt = 0; nt < 4; ++nt) {
        acc[mt][nt] = __builtin_amdgcn_mfma_f32_16x16x32_bf16(ah[mt], bh[nt], acc[mt][nt], 0, 0, 0);
        acc[mt][nt] = __builtin_amdgcn_mfma_f32_16x16x32_bf16(al[mt], bh[nt], acc[mt][nt], 0, 0, 0);
      }
    __syncthreads();
  }

  const long col  = bcol + wc * 64 + m15;
  const long rowb = brow + wr * 64 + (lane >> 4) * 4;
#pragma unroll
  for (int mt = 0; mt < 4; ++mt)
#pragma unroll
    for (int nt = 0; nt < 4; ++nt)
#pragma unroll
      for (int i = 0; i < 4; ++i) {
        const float e = __expf(acc[mt][nt][i] * SCALE);
        unsigned short hh, ll;
        split1(e, hh, ll);
        const long idx = (rowb + mt * 16 + i) * (long)N + col + nt * 16;
        Eh[idx] = hh;
        El[idx] = ll;
      }
}

// ---------------- fused kv chunk: pkv_c[d][e] = sum_m E[m][d] * v[m][e]
// E pre-split (hi/lo bf16, from gemm_2t_exp); V bf16. Column sums Z_c[d] via
// a ones-column MFMA. Persistent MK/MV rows computed in-kernel (f32).
__global__ __launch_bounds__(256) void kv_chunk(const unsigned short* __restrict__ Ehg,
                                                const unsigned short* __restrict__ Elg,
                                                const unsigned short* __restrict__ vb,
                                                const float* __restrict__ MK,
                                                const float* __restrict__ MV,
                                                float* __restrict__ pkv,
                                                float* __restrict__ pZ) {
  const int bh = blockIdx.x, c = blockIdx.y;
  const int b = bh >> 4, h = bh & 15;
  const int tid = threadIdx.x;
  const int w = tid >> 6, lane = tid & 63;
  // m-contiguous transposed tiles, row stride 18 u32 (72B: 8B-aligned reads,
  // 2-way read banks, 4-way write banks)
  __shared__ unsigned Eh_s[64 * 18];
  __shared__ unsigned El_s[64 * 18];
  __shared__ unsigned Vt_s[64 * 18];

  // staging map: thread handles m-pair (m2, m2+1), 4 d's
  const int m2  = (tid >> 4) * 2;     // 0..30 even
  const int d0s = (tid & 15) * 4;     // 0..60

  float4v acc[4];
#pragma unroll
  for (int i = 0; i < 4; ++i) acc[i] = (float4v){0.f, 0.f, 0.f, 0.f};
  float4v zacc = (float4v){0.f, 0.f, 0.f, 0.f};

  short8 ones;
#pragma unroll
  for (int i = 0; i < 8; ++i) ones[i] = (short)0x3F80;   // bf16 1.0

  const int m15 = lane & 15, q8 = (lane >> 4) * 8;
  const int fragoff = m15 * 18 + (q8 >> 1);               // u32 offset within strip

  for (int t = 0; t < CH / 32; ++t) {
    const int mt0 = c * CH + t * 32;                      // 32-aligned -> tile uniform branch
    unsigned short eh0[4], eh1[4], el0[4], el1[4], vv0[4], vv1[4];
    if (mt0 < NSEQ) {
      const long base0 = ((long)(b * NSEQ) + mt0 + m2) * DMODEL + h * DK + d0s;
      short4v a0 = *(const short4v*)(Ehg + base0);
      short4v a1 = *(const short4v*)(Ehg + base0 + DMODEL);
      short4v b0 = *(const short4v*)(Elg + base0);
      short4v b1 = *(const short4v*)(Elg + base0 + DMODEL);
      short4v c0 = *(const short4v*)(vb + base0);
      short4v c1 = *(const short4v*)(vb + base0 + DMODEL);
#pragma unroll
      for (int j = 0; j < 4; ++j) {
        eh0[j] = (unsigned short)a0[j]; eh1[j] = (unsigned short)a1[j];
        el0[j] = (unsigned short)b0[j]; el1[j] = (unsigned short)b1[j];
        vv0[j] = (unsigned short)c0[j]; vv1[j] = (unsigned short)c1[j];
      }
    } else {
      const long base0 = ((long)h * NP + (mt0 - NSEQ) + m2) * DK + d0s;
      float4v ka = *(const float4v*)(MK + base0);
      float4v kb = *(const float4v*)(MK + base0 + DK);
      float4v va = *(const float4v*)(MV + base0);
      float4v vc = *(const float4v*)(MV + base0 + DK);
#pragma unroll
      for (int j = 0; j < 4; ++j) {
        split1(__expf(ka[j] * SCALE), eh0[j], el0[j]);
        split1(__expf(kb[j] * SCALE), eh1[j], el1[j]);
        vv0[j] = f2b(va[j]); vv1[j] = f2b(vc[j]);
      }
    }
    __syncthreads();   // previous tile's fragment reads complete
#pragma unroll
    for (int j = 0; j < 4; ++j) {
      const int off = (d0s + j) * 18 + (m2 >> 1);
      Eh_s[off] = (unsigned)eh0[j] | ((unsigned)eh1[j] << 16);
      El_s[off] = (unsigned)el0[j] | ((unsigned)el1[j] << 16);
      Vt_s[off] = (unsigned)vv0[j] | ((unsigned)vv1[j] << 16);
    }
    __syncthreads();
    const short8 a_h = ld8(&Eh_s[w * 16 * 18 + fragoff]);
    const short8 a_l = ld8(&El_s[w * 16 * 18 + fragoff]);
#pragma unroll
    for (int n = 0; n < 4; ++n) {
      const short8 bv = ld8(&Vt_s[n * 16 * 18 + fragoff]);
      acc[n] = __builtin_amdgcn_mfma_f32_16x16x32_bf16(a_h, bv, acc[n], 0, 0, 0);
      acc[n] = __builtin_amdgcn_mfma_f32_16x16x32_bf16(a_l, bv, acc[n], 0, 0, 0);
    }
    zacc = __builtin_amdgcn_mfma_f32_16x16x32_bf16(a_h, ones, zacc, 0, 0, 0);
    zacc = __builtin_amdgcn_mfma_f32_16x16x32_bf16(a_l, ones, zacc, 0, 0, 0);
  }

  // C/D layout: col = lane&15, row = (lane>>4)*4 + i
  const int row = (lane >> 4) * 4;
  float* pk = pkv + (((long)(bh * NCH + c)) << 12);
#pragma unroll
  for (int n = 0; n < 4; ++n)
#pragma unroll
    for (int i = 0; i < 4; ++i)
      pk[(w * 16 + row + i) * 64 + n * 16 + m15] = acc[n][i];
  if (m15 == 0) {
#pragma unroll
    for (int i = 0; i < 4; ++i)
      pZ[(bh * NCH + c) * 64 + w * 16 + row + i] = zacc[i];
  }
}

// ---------------- fused Q projection + beta softmax + z = beta @ kv.
// A = Qh bf16 [16384,1024], B = WQh bf16 [1024,1024]; kvT f32 [64][e*64+d];
// writes y bf16 [16384,1024]. Each wave's tile = 64 rows x one full head.
__global__ __launch_bounds__(256, 3) void gemm_q_beta(const unsigned short* __restrict__ A,
                                                      const unsigned short* __restrict__ B,
                                                      const float* __restrict__ kvT,
                                                      unsigned short* __restrict__ y) {
  __shared__ unsigned short pool[17408];   // 34816 B: As/Bs during K-loop, beta after
  unsigned short* As = pool;               // 4096 u16
  unsigned short* Bs = pool + 4096;        // 4096 u16
  unsigned short* beta_s = pool;           // [128][136] u16

  const int tid = threadIdx.x;
  const int w = tid >> 6, lane = tid & 63;
  const int wr = w >> 1, wc = w & 1;
  long brow, bcol; swz(blockIdx.x, brow, bcol);
  const int K = 1024;

  const int r0 = tid >> 2;
  const int kc = (tid & 3) * 8;
  const unsigned short* Ag0 = A + (brow + r0) * (long)K + kc;
  const unsigned short* Ag1 = Ag0 + 64L * K;
  const unsigned short* Bg0 = B + (bcol + r0) * (long)K + kc;
  const unsigned short* Bg1 = Bg0 + 64L * K;
  unsigned short* As0 = &As[w * 512];
  unsigned short* Bs0 = &Bs[w * 512];

  float4v acc[4][4];
#pragma unroll
  for (int i = 0; i < 4; ++i)
#pragma unroll
    for (int j = 0; j < 4; ++j) acc[i][j] = (float4v){0.f, 0.f, 0.f, 0.f};

  const int m15 = lane & 15, q8 = (lane >> 4) * 8, q4 = (lane >> 4) * 4;

  for (int k0 = 0; k0 < K; k0 += 32) {
    gload16(Ag0 + k0, As0);
    gload16(Ag1 + k0, As0 + 2048);
    gload16(Bg0 + k0, Bs0);
    gload16(Bg1 + k0, Bs0 + 2048);
    __syncthreads();
    short8 af[4], bfr[4];
#pragma unroll
    for (int t = 0; t < 4; ++t) {
      af[t]  = *(const short8*)&As[(wr * 64 + t * 16 + m15) * 32 + q8];
      bfr[t] = *(const short8*)&Bs[(wc * 64 + t * 16 + m15) * 32 + q8];
    }
#pragma unroll
    for (int mt = 0; mt < 4; ++mt)
#pragma unroll
      for (int nt = 0; nt < 4; ++nt)
        acc[mt][nt] = __builtin_amdgcn_mfma_f32_16x16x32_bf16(af[mt], bfr[nt], acc[mt][nt], 0, 0, 0);
    __syncthreads();   // all waves done reading As/Bs -> safe to overlay beta
  }

  // --- softmax over dk per row (4 regs + shfl_xor across the 16-lane group) ---
#pragma unroll
  for (int mt = 0; mt < 4; ++mt) {
#pragma unroll
    for (int i = 0; i < 4; ++i) {
      float mx = fmaxf(fmaxf(acc[mt][0][i], acc[mt][1][i]),
                       fmaxf(acc[mt][2][i], acc[mt][3][i]));
#pragma unroll
      for (int s = 1; s < 16; s <<= 1) mx = fmaxf(mx, __shfl_xor(mx, s));
      float e[4], sum = 0.f;
#pragma unroll
      for (int nt = 0; nt < 4; ++nt) { e[nt] = __expf(acc[mt][nt][i] - mx); sum += e[nt]; }
#pragma unroll
      for (int s = 1; s < 16; s <<= 1) sum += __shfl_xor(sum, s);
      const float inv = 1.f / sum;
      const int r = wr * 64 + mt * 16 + q4 + i;
#pragma unroll
      for (int nt = 0; nt < 4; ++nt)
        beta_s[r * 136 + wc * 64 + nt * 16 + m15] = f2b(e[nt] * inv);
    }
  }
  __syncthreads();

  // --- z = beta @ kv (kv hi/lo from L2-resident kvT, straight to registers) ---
  const int hb = (int)(bcol >> 6) + wc;        // head 0..15
  const int bb = (int)(brow >> 12);            // batch 0..3
  const long kvbase = ((long)(bb * 16 + hb)) << 12;

  float4v zacc[4][4];
#pragma unroll
  for (int i = 0; i < 4; ++i)
#pragma unroll
    for (int j = 0; j < 4; ++j) zacc[i][j] = (float4v){0.f, 0.f, 0.f, 0.f};

#pragma unroll
  for (int nt = 0; nt < 4; ++nt) {
    short8 bh2[2], bl2[2];
#pragma unroll
    for (int kk = 0; kk < 2; ++kk) {
      const float* kp = kvT + kvbase + (nt * 16 + m15) * 64 + kk * 32 + q8;
      float4v k0v = *(const float4v*)kp;
      float4v k1v = *(const float4v*)(kp + 4);
      unsigned short hh[8], ll[8];
#pragma unroll
      for (int j = 0; j < 4; ++j) { split1(k0v[j], hh[j], ll[j]); split1(k1v[j], hh[4 + j], ll[4 + j]); }
#pragma unroll
      for (int j = 0; j < 8; ++j) { bh2[kk][j] = (short)hh[j]; bl2[kk][j] = (short)ll[j]; }
    }
#pragma unroll
    for (int mt = 0; mt < 4; ++mt) {
#pragma unroll
      for (int kk = 0; kk < 2; ++kk) {
        const short8 af = *(const short8*)&beta_s[(wr * 64 + mt * 16 + m15) * 136 + wc * 64 + kk * 32 + q8];
        zacc[mt][nt] = __builtin_amdgcn_mfma_f32_16x16x32_bf16(af, bh2[kk], zacc[mt][nt], 0, 0, 0);
        zacc[mt][nt] = __builtin_amdgcn_mfma_f32_16x16x32_bf16(af, bl2[kk], zacc[mt][nt], 0, 0, 0);
      }
    }
  }

  // --- write y: row = brow + wr*64 + mt*16 + q4 + i, col = hb*64 + nt*16 + m15 ---
#pragma unroll
  for (int mt = 0; mt < 4; ++mt)
#pragma unroll
    for (int nt = 0; nt < 4; ++nt)
#pragma unroll
      for (int i = 0; i < 4; ++i)
        y[(brow + wr * 64 + mt * 16 + q4 + i) * (long)DMODEL + hb * 64 + nt * 16 + m15] =
            f2b(zacc[mt][nt][i]);
}

extern "C" void kernel_launch(void* const* d_in, const int* in_sizes, int n_in,
                              void* d_out, int out_size, void* d_ws, size_t ws_size,
                              hipStream_t stream) {
  const float* Q  = (const float*)d_in[0];
  const float* Kk = (const float*)d_in[1];
  const float* V  = (const float*)d_in[2];
  const float* WQ = (const float*)d_in[3];
  const float* WK = (const float*)d_in[4];
  const float* WV = (const float*)d_in[5];
  const float* WO = (const float*)d_in[6];
  const float* MK = (const float*)d_in[7];
  const float* MV = (const float*)d_in[8];

  char* ws = (char*)d_ws;
  // Region plan (time-multiplexed; max offset ~153 MiB):
  //  R1 [0,32M):    Kh -> Vh -> pkv(25.2M f32)
  //  R2 [32M,64M):  Kl -> vb -> yb
  //  Eh [64M,96M):  Eh -> Qh
  //  El [96M,128M): El
  //  WB [128M,144M): weight hi/lo splits (hi/lo pairs at 4MB stride)
  //  S  [144M,...):  pZ / kvT
  //  d_out is written only by the final gemm.
  unsigned short* R1 = (unsigned short*)(ws);
  unsigned short* R2 = (unsigned short*)(ws + 33554432);
  unsigned short* Eh = (unsigned short*)(ws + 67108864);
  unsigned short* El = (unsigned short*)(ws + 100663296);
  const long WB = 134217728;
  unsigned short* Wbase = (unsigned short*)(ws + WB);
  unsigned short* WQh = Wbase;
  unsigned short* WKh = (unsigned short*)(ws + WB + 4194304);
  unsigned short* WVh = (unsigned short*)(ws + WB + 8388608);
  unsigned short* WOh = (unsigned short*)(ws + WB + 12582912);
  const long S = 150994944;
  float* pZ  = (float*)(ws + S);               // 64*24*64*4 = 393 KB
  float* kvT = (float*)(ws + S + 8683520);     // 1 MB
  float* pkv = (float*)R1;                     // 64*24*4096*4 = 25.2 MB
  unsigned short* Qh = Eh;                     // Qh overlays Eh (dead after kv_chunk)

  const dim3 blk(256);
  const int N = 1024, K = 1024;
  const int NELEM = 4 * NSEQ * DMODEL;   // 16.7M per input tensor

  // merged: K input hi/lo split + all four weight splits (one launch)
  cvt_kw<<<10240, blk, 0, stream>>>(Kk, R1, R2, WQ, WK, WV, WO, Wbase);

  // K projection + fused exp: 2-term GEMM -> Eh/El (bf16 split of exp(k*SCALE))
  gemm_2t_exp<<<1024, blk, 0, stream>>>(R1, R2, WKh, Eh, El, N, K);

  // V projection: hi-only bf16 in R1 (Kh dead), GEMM -> vb in R2 (Kl dead)
  cvt_hi<<<8192, blk, 0, stream>>>(V, R1, NELEM);
  gemm_bt<1><<<1024, blk, 0, stream>>>(R1, WVh, (void*)R2, N, K);

  // fused kv: per-chunk E^T@V via MFMA; pkv in R1 (Vh dead)
  kv_chunk<<<dim3(64, NCH), blk, 0, stream>>>(Eh, El, R2, MK, MV, pkv, pZ);

  // merged: Q -> bf16 hi into Eh region (Eh dead) + reduce_kv2 -> kvT
  cvt_q_reduce<<<9216, blk, 0, stream>>>(Q, Qh, pkv, pZ, kvT);

  // Q projection + beta softmax + z, fused: yb in R2 (vb dead)
  gemm_q_beta<<<1024, blk, 0, stream>>>(Qh, WQh, kvT, R2);

  // output projection -> d_out (single writer of d_out)
  gemm_bt<0><<<1024, blk, 0, stream>>>(R2, WOh, (float*)d_out, N, K);
}

// Round 8
// 463.327 us; speedup vs baseline: 2.6509x; 2.6509x over previous
//
#include <hip/hip_runtime.h>
#include <stdint.h>

typedef __attribute__((ext_vector_type(8))) short short8;
typedef __attribute__((ext_vector_type(4))) short short4v;
typedef __attribute__((ext_vector_type(4))) float float4v;
typedef __attribute__((ext_vector_type(4))) unsigned int uint4v;

#define NSEQ   4096
#define DMODEL 1024
#define NHEAD  16
#define DK     64
#define NP     512
#define MTOT   4608
#define NCH    24
#define CH     192   // 4608 / 24, multiple of 32
#define SCALE  2.8284271247461903f   // 64^0.25

__device__ __forceinline__ float b2f(unsigned short u) {
  union { unsigned u; float f; } x; x.u = ((unsigned)u) << 16; return x.f;
}
__device__ __forceinline__ unsigned short f2b(float f) {
  union { float f; unsigned u; } x; x.f = f;
  unsigned r = x.u + 0x7fffu + ((x.u >> 16) & 1u);
  return (unsigned short)(r >> 16);
}
__device__ __forceinline__ void split1(float x, unsigned short& h, unsigned short& l) {
  h = f2b(x);
  l = f2b(x - b2f(h));
}
__device__ __forceinline__ void gload16(const void* g, void* l) {
  __builtin_amdgcn_global_load_lds((const __attribute__((address_space(1))) void*)g,
                                   (__attribute__((address_space(3))) void*)l,
                                   16, 0, 0);
}
// 16B fragment from an 8B-aligned LDS address (stride-18-u32 rows): two b64 reads.
__device__ __forceinline__ short8 ld8(const unsigned* p) {
  union { short8 s; short4v h[2]; } u;
  u.h[0] = *(const short4v*)p;
  u.h[1] = *(const short4v*)(p + 2);
  return u.s;
}

// XCD-aware swizzle: lin%8 = hw XCD (round-robin); each XCD covers 16
// contiguous row-strips, col fastest -> A strip fetched once per XCD L2.
__device__ __forceinline__ void swz(int lin, long& brow, long& bcol) {
  brow = (long)(((lin & 7) << 4) | (lin >> 6)) * 128;
  bcol = (long)((lin >> 3) & 7) * 128;
}

__device__ __forceinline__ void split8_store(const float4v& x0, const float4v& x1,
                                             unsigned short* hi, unsigned short* lo, int i) {
  unsigned short h[8], l[8];
#pragma unroll
  for (int j = 0; j < 4; ++j) split1(x0[j], h[j], l[j]);
#pragma unroll
  for (int j = 0; j < 4; ++j) split1(x1[j], h[4 + j], l[4 + j]);
  uint4v ph, pl;
#pragma unroll
  for (int j = 0; j < 4; ++j) {
    ph[j] = (unsigned)h[2 * j] | ((unsigned)h[2 * j + 1] << 16);
    pl[j] = (unsigned)l[2 * j] | ((unsigned)l[2 * j + 1] << 16);
  }
  *(uint4v*)(hi + i) = ph;
  *(uint4v*)(lo + i) = pl;
}

// ---------------- merged: K input hi/lo split (blocks 0..8191) + all four
// weight hi/lo splits (blocks 8192..10239; 512 blocks per weight).
__global__ __launch_bounds__(256) void cvt_kw(const float* __restrict__ Kin,
                                              unsigned short* __restrict__ Khi,
                                              unsigned short* __restrict__ Klo,
                                              const float* __restrict__ w0,
                                              const float* __restrict__ w1,
                                              const float* __restrict__ w2,
                                              const float* __restrict__ w3,
                                              unsigned short* __restrict__ hibase) {
  const int bid = blockIdx.x;
  if (bid < 8192) {
    const int i = (bid * 256 + threadIdx.x) * 8;
    float4v x0 = *(const float4v*)(Kin + i);
    float4v x1 = *(const float4v*)(Kin + i + 4);
    split8_store(x0, x1, Khi, Klo, i);
  } else {
    const int wb = bid - 8192;
    const int y = wb >> 9;
    const float* s = (y == 0) ? w0 : (y == 1) ? w1 : (y == 2) ? w2 : w3;
    unsigned short* hi = hibase + (long)y * 2097152;
    unsigned short* lo = hi + 1048576;
    const int i = ((wb & 511) * 256 + threadIdx.x) * 8;
    float4v x0 = *(const float4v*)(s + i);
    float4v x1 = *(const float4v*)(s + i + 4);
    split8_store(x0, x1, hi, lo, i);
  }
}

// ---------------- f32 -> bf16 hi only (V input)
__global__ __launch_bounds__(256) void cvt_hi(const float* __restrict__ s,
                                              unsigned short* __restrict__ hi, int n) {
  const int i = (blockIdx.x * 256 + threadIdx.x) * 8;
  if (i + 8 > n) return;
  float4v x0 = *(const float4v*)(s + i);
  float4v x1 = *(const float4v*)(s + i + 4);
  uint4v ph;
  ph[0] = (unsigned)f2b(x0[0]) | ((unsigned)f2b(x0[1]) << 16);
  ph[1] = (unsigned)f2b(x0[2]) | ((unsigned)f2b(x0[3]) << 16);
  ph[2] = (unsigned)f2b(x1[0]) | ((unsigned)f2b(x1[1]) << 16);
  ph[3] = (unsigned)f2b(x1[2]) | ((unsigned)f2b(x1[3]) << 16);
  *(uint4v*)(hi + i) = ph;
}

// ---------------- merged: Q input -> bf16 hi (blocks 0..8191) + reduce_kv2
// (blocks 8192..9215): reduce chunk kv + Z, normalize, write kvT[bh][e][d].
__global__ __launch_bounds__(256) void cvt_q_reduce(const float* __restrict__ Qin,
                                                    unsigned short* __restrict__ Qhi,
                                                    const float* __restrict__ pkv,
                                                    const float* __restrict__ pZ,
                                                    float* __restrict__ kvT) {
  const int bid = blockIdx.x;
  if (bid < 8192) {
    const int i = (bid * 256 + threadIdx.x) * 8;
    float4v x0 = *(const float4v*)(Qin + i);
    float4v x1 = *(const float4v*)(Qin + i + 4);
    uint4v ph;
    ph[0] = (unsigned)f2b(x0[0]) | ((unsigned)f2b(x0[1]) << 16);
    ph[1] = (unsigned)f2b(x0[2]) | ((unsigned)f2b(x0[3]) << 16);
    ph[2] = (unsigned)f2b(x1[0]) | ((unsigned)f2b(x1[1]) << 16);
    ph[3] = (unsigned)f2b(x1[2]) | ((unsigned)f2b(x1[3]) << 16);
    *(uint4v*)(Qhi + i) = ph;
  } else {
    const int idx = (bid - 8192) * 256 + threadIdx.x;
    const int bh = idx >> 12, de = idx & 4095, d = de >> 6, e = de & 63;
    float s = 0.f;
#pragma unroll
    for (int c = 0; c < NCH; ++c) s += pkv[(((long)(bh * NCH + c)) << 12) + de];
    float Z = 0.f;
#pragma unroll
    for (int c = 0; c < NCH; ++c) Z += pZ[(bh * NCH + c) * 64 + d];
    kvT[((long)bh << 12) + e * 64 + d] = s / Z;
  }
}

// ---------------- pure-bf16 NT GEMM (m97 path): C[M,N] = A[M,K] @ B[N,K]^T.
// NOTE: (256,4) is the register ceiling — unified VGPR/AGPR file means true
// usage is ~60 VGPR + 64 AGPR acc = 124 regs; budget at 4 waves/EU = 128.
// (256,6) caps at 85 -> accumulator spills to scratch (R7: 19x HBM traffic).
template<int BF16OUT>
__global__ __launch_bounds__(256, 4) void gemm_bt(const unsigned short* __restrict__ A,
                                                  const unsigned short* __restrict__ B,
                                                  void* __restrict__ Cv,
                                                  int N, int K) {
  __shared__ unsigned short As[4096];
  __shared__ unsigned short Bs[4096];
  const int tid = threadIdx.x;
  const int w = tid >> 6, lane = tid & 63;
  const int wr = w >> 1, wc = w & 1;
  long brow, bcol; swz(blockIdx.x, brow, bcol);

  const int r0 = tid >> 2;
  const int kc = (tid & 3) * 8;
  const unsigned short* Ag0 = A + (brow + r0) * (long)K + kc;
  const unsigned short* Ag1 = Ag0 + 64L * K;
  const unsigned short* Bg0 = B + (bcol + r0) * (long)K + kc;
  const unsigned short* Bg1 = Bg0 + 64L * K;
  unsigned short* As0 = &As[w * 512];
  unsigned short* Bs0 = &Bs[w * 512];

  float4v acc[4][4];
#pragma unroll
  for (int i = 0; i < 4; ++i)
#pragma unroll
    for (int j = 0; j < 4; ++j) acc[i][j] = (float4v){0.f, 0.f, 0.f, 0.f};

  const int m15 = lane & 15, q8 = (lane >> 4) * 8;

  for (int k0 = 0; k0 < K; k0 += 32) {
    gload16(Ag0 + k0, As0);
    gload16(Ag1 + k0, As0 + 2048);
    gload16(Bg0 + k0, Bs0);
    gload16(Bg1 + k0, Bs0 + 2048);
    __syncthreads();
    short8 af[4], bfr[4];
#pragma unroll
    for (int t = 0; t < 4; ++t) {
      af[t]  = *(const short8*)&As[(wr * 64 + t * 16 + m15) * 32 + q8];
      bfr[t] = *(const short8*)&Bs[(wc * 64 + t * 16 + m15) * 32 + q8];
    }
#pragma unroll
    for (int mt = 0; mt < 4; ++mt)
#pragma unroll
      for (int nt = 0; nt < 4; ++nt)
        acc[mt][nt] = __builtin_amdgcn_mfma_f32_16x16x32_bf16(af[mt], bfr[nt], acc[mt][nt], 0, 0, 0);
    __syncthreads();
  }

  const long col  = bcol + wc * 64 + m15;
  const long rowb = brow + wr * 64 + (lane >> 4) * 4;
  if constexpr (BF16OUT) {
    unsigned short* C = (unsigned short*)Cv;
#pragma unroll
    for (int mt = 0; mt < 4; ++mt)
#pragma unroll
      for (int nt = 0; nt < 4; ++nt)
#pragma unroll
        for (int i = 0; i < 4; ++i)
          C[(rowb + mt * 16 + i) * (long)N + col + nt * 16] = f2b(acc[mt][nt][i]);
  } else {
    float* C = (float*)Cv;
#pragma unroll
    for (int mt = 0; mt < 4; ++mt)
#pragma unroll
      for (int nt = 0; nt < 4; ++nt)
#pragma unroll
        for (int i = 0; i < 4; ++i)
          C[(rowb + mt * 16 + i) * (long)N + col + nt * 16] = acc[mt][nt][i];
  }
}

// ---------------- 2-term split-bf16 NT GEMM (K projection), fused exp epilogue:
// k = Ah*Bh^T + Al*Bh^T (exact-A @ bf16-W); writes Eh/El = split(exp(k*SCALE)).
// (256,4) register ceiling — see gemm_bt note.
__global__ __launch_bounds__(256, 4) void gemm_2t_exp(const unsigned short* __restrict__ Ah,
                                                      const unsigned short* __restrict__ Al,
                                                      const unsigned short* __restrict__ Bh,
                                                      unsigned short* __restrict__ Eh,
                                                      unsigned short* __restrict__ El,
                                                      int N, int K) {
  __shared__ unsigned short Ash[4096];
  __shared__ unsigned short Asl[4096];
  __shared__ unsigned short Bsh[4096];
  const int tid = threadIdx.x;
  const int w = tid >> 6, lane = tid & 63;
  const int wr = w >> 1, wc = w & 1;
  long brow, bcol; swz(blockIdx.x, brow, bcol);

  const int r0 = tid >> 2;
  const int kc = (tid & 3) * 8;
  const unsigned short* Ahg0 = Ah + (brow + r0) * (long)K + kc;
  const unsigned short* Ahg1 = Ahg0 + 64L * K;
  const unsigned short* Alg0 = Al + (brow + r0) * (long)K + kc;
  const unsigned short* Alg1 = Alg0 + 64L * K;
  const unsigned short* Bhg0 = Bh + (bcol + r0) * (long)K + kc;
  const unsigned short* Bhg1 = Bhg0 + 64L * K;
  unsigned short* Ash0 = &Ash[w * 512];
  unsigned short* Asl0 = &Asl[w * 512];
  unsigned short* Bsh0 = &Bsh[w * 512];

  float4v acc[4][4];
#pragma unroll
  for (int i = 0; i < 4; ++i)
#pragma unroll
    for (int j = 0; j < 4; ++j) acc[i][j] = (float4v){0.f, 0.f, 0.f, 0.f};

  const int m15 = lane & 15, q8 = (lane >> 4) * 8;

  for (int k0 = 0; k0 < K; k0 += 32) {
    gload16(Ahg0 + k0, Ash0);
    gload16(Ahg1 + k0, Ash0 + 2048);
    gload16(Alg0 + k0, Asl0);
    gload16(Alg1 + k0, Asl0 + 2048);
    gload16(Bhg0 + k0, Bsh0);
    gload16(Bhg1 + k0, Bsh0 + 2048);
    __syncthreads();
    short8 ah[4], al[4], bh[4];
#pragma unroll
    for (int t = 0; t < 4; ++t) {
      const int ar = (wr * 64 + t * 16 + m15) * 32 + q8;
      const int br = (wc * 64 + t * 16 + m15) * 32 + q8;
      ah[t] = *(const short8*)&Ash[ar];
      al[t] = *(const short8*)&Asl[ar];
      bh[t] = *(const short8*)&Bsh[br];
    }
#pragma unroll
    for (int mt = 0; mt < 4; ++mt)
#pragma unroll
      for (int nt = 0; nt < 4; ++nt) {
        acc[mt][nt] = __builtin_amdgcn_mfma_f32_16x16x32_bf16(ah[mt], bh[nt], acc[mt][nt], 0, 0, 0);
        acc[mt][nt] = __builtin_amdgcn_mfma_f32_16x16x32_bf16(al[mt], bh[nt], acc[mt][nt], 0, 0, 0);
      }
    __syncthreads();
  }

  const long col  = bcol + wc * 64 + m15;
  const long rowb = brow + wr * 64 + (lane >> 4) * 4;
#pragma unroll
  for (int mt = 0; mt < 4; ++mt)
#pragma unroll
    for (int nt = 0; nt < 4; ++nt)
#pragma unroll
      for (int i = 0; i < 4; ++i) {
        const float e = __expf(acc[mt][nt][i] * SCALE);
        unsigned short hh, ll;
        split1(e, hh, ll);
        const long idx = (rowb + mt * 16 + i) * (long)N + col + nt * 16;
        Eh[idx] = hh;
        El[idx] = ll;
      }
}

// ---------------- fused kv chunk: pkv_c[d][e] = sum_m E[m][d] * v[m][e]
// E pre-split (hi/lo bf16, from gemm_2t_exp); V bf16. Column sums Z_c[d] via
// a ones-column MFMA. Persistent MK/MV rows computed in-kernel (f32).
__global__ __launch_bounds__(256) void kv_chunk(const unsigned short* __restrict__ Ehg,
                                                const unsigned short* __restrict__ Elg,
                                                const unsigned short* __restrict__ vb,
                                                const float* __restrict__ MK,
                                                const float* __restrict__ MV,
                                                float* __restrict__ pkv,
                                                float* __restrict__ pZ) {
  const int bh = blockIdx.x, c = blockIdx.y;
  const int b = bh >> 4, h = bh & 15;
  const int tid = threadIdx.x;
  const int w = tid >> 6, lane = tid & 63;
  // m-contiguous transposed tiles, row stride 18 u32 (72B: 8B-aligned reads,
  // 2-way read banks, 4-way write banks)
  __shared__ unsigned Eh_s[64 * 18];
  __shared__ unsigned El_s[64 * 18];
  __shared__ unsigned Vt_s[64 * 18];

  // staging map: thread handles m-pair (m2, m2+1), 4 d's
  const int m2  = (tid >> 4) * 2;     // 0..30 even
  const int d0s = (tid & 15) * 4;     // 0..60

  float4v acc[4];
#pragma unroll
  for (int i = 0; i < 4; ++i) acc[i] = (float4v){0.f, 0.f, 0.f, 0.f};
  float4v zacc = (float4v){0.f, 0.f, 0.f, 0.f};

  short8 ones;
#pragma unroll
  for (int i = 0; i < 8; ++i) ones[i] = (short)0x3F80;   // bf16 1.0

  const int m15 = lane & 15, q8 = (lane >> 4) * 8;
  const int fragoff = m15 * 18 + (q8 >> 1);               // u32 offset within strip

  for (int t = 0; t < CH / 32; ++t) {
    const int mt0 = c * CH + t * 32;                      // 32-aligned -> tile uniform branch
    unsigned short eh0[4], eh1[4], el0[4], el1[4], vv0[4], vv1[4];
    if (mt0 < NSEQ) {
      const long base0 = ((long)(b * NSEQ) + mt0 + m2) * DMODEL + h * DK + d0s;
      short4v a0 = *(const short4v*)(Ehg + base0);
      short4v a1 = *(const short4v*)(Ehg + base0 + DMODEL);
      short4v b0 = *(const short4v*)(Elg + base0);
      short4v b1 = *(const short4v*)(Elg + base0 + DMODEL);
      short4v c0 = *(const short4v*)(vb + base0);
      short4v c1 = *(const short4v*)(vb + base0 + DMODEL);
#pragma unroll
      for (int j = 0; j < 4; ++j) {
        eh0[j] = (unsigned short)a0[j]; eh1[j] = (unsigned short)a1[j];
        el0[j] = (unsigned short)b0[j]; el1[j] = (unsigned short)b1[j];
        vv0[j] = (unsigned short)c0[j]; vv1[j] = (unsigned short)c1[j];
      }
    } else {
      const long base0 = ((long)h * NP + (mt0 - NSEQ) + m2) * DK + d0s;
      float4v ka = *(const float4v*)(MK + base0);
      float4v kb = *(const float4v*)(MK + base0 + DK);
      float4v va = *(const float4v*)(MV + base0);
      float4v vc = *(const float4v*)(MV + base0 + DK);
#pragma unroll
      for (int j = 0; j < 4; ++j) {
        split1(__expf(ka[j] * SCALE), eh0[j], el0[j]);
        split1(__expf(kb[j] * SCALE), eh1[j], el1[j]);
        vv0[j] = f2b(va[j]); vv1[j] = f2b(vc[j]);
      }
    }
    __syncthreads();   // previous tile's fragment reads complete
#pragma unroll
    for (int j = 0; j < 4; ++j) {
      const int off = (d0s + j) * 18 + (m2 >> 1);
      Eh_s[off] = (unsigned)eh0[j] | ((unsigned)eh1[j] << 16);
      El_s[off] = (unsigned)el0[j] | ((unsigned)el1[j] << 16);
      Vt_s[off] = (unsigned)vv0[j] | ((unsigned)vv1[j] << 16);
    }
    __syncthreads();
    const short8 a_h = ld8(&Eh_s[w * 16 * 18 + fragoff]);
    const short8 a_l = ld8(&El_s[w * 16 * 18 + fragoff]);
#pragma unroll
    for (int n = 0; n < 4; ++n) {
      const short8 bv = ld8(&Vt_s[n * 16 * 18 + fragoff]);
      acc[n] = __builtin_amdgcn_mfma_f32_16x16x32_bf16(a_h, bv, acc[n], 0, 0, 0);
      acc[n] = __builtin_amdgcn_mfma_f32_16x16x32_bf16(a_l, bv, acc[n], 0, 0, 0);
    }
    zacc = __builtin_amdgcn_mfma_f32_16x16x32_bf16(a_h, ones, zacc, 0, 0, 0);
    zacc = __builtin_amdgcn_mfma_f32_16x16x32_bf16(a_l, ones, zacc, 0, 0, 0);
  }

  // C/D layout: col = lane&15, row = (lane>>4)*4 + i
  const int row = (lane >> 4) * 4;
  float* pk = pkv + (((long)(bh * NCH + c)) << 12);
#pragma unroll
  for (int n = 0; n < 4; ++n)
#pragma unroll
    for (int i = 0; i < 4; ++i)
      pk[(w * 16 + row + i) * 64 + n * 16 + m15] = acc[n][i];
  if (m15 == 0) {
#pragma unroll
    for (int i = 0; i < 4; ++i)
      pZ[(bh * NCH + c) * 64 + w * 16 + row + i] = zacc[i];
  }
}

// ---------------- fused Q projection + beta softmax + z = beta @ kv.
// A = Qh bf16 [16384,1024], B = WQh bf16 [1024,1024]; kvT f32 [64][e*64+d];
// writes y bf16 [16384,1024]. Each wave's tile = 64 rows x one full head.
// (256,2): two acc arrays (acc + zacc) keep register pressure high.
__global__ __launch_bounds__(256, 2) void gemm_q_beta(const unsigned short* __restrict__ A,
                                                      const unsigned short* __restrict__ B,
                                                      const float* __restrict__ kvT,
                                                      unsigned short* __restrict__ y) {
  __shared__ unsigned short pool[17408];   // 34816 B: As/Bs during K-loop, beta after
  unsigned short* As = pool;               // 4096 u16
  unsigned short* Bs = pool + 4096;        // 4096 u16
  unsigned short* beta_s = pool;           // [128][136] u16

  const int tid = threadIdx.x;
  const int w = tid >> 6, lane = tid & 63;
  const int wr = w >> 1, wc = w & 1;
  long brow, bcol; swz(blockIdx.x, brow, bcol);
  const int K = 1024;

  const int r0 = tid >> 2;
  const int kc = (tid & 3) * 8;
  const unsigned short* Ag0 = A + (brow + r0) * (long)K + kc;
  const unsigned short* Ag1 = Ag0 + 64L * K;
  const unsigned short* Bg0 = B + (bcol + r0) * (long)K + kc;
  const unsigned short* Bg1 = Bg0 + 64L * K;
  unsigned short* As0 = &As[w * 512];
  unsigned short* Bs0 = &Bs[w * 512];

  float4v acc[4][4];
#pragma unroll
  for (int i = 0; i < 4; ++i)
#pragma unroll
    for (int j = 0; j < 4; ++j) acc[i][j] = (float4v){0.f, 0.f, 0.f, 0.f};

  const int m15 = lane & 15, q8 = (lane >> 4) * 8, q4 = (lane >> 4) * 4;

  for (int k0 = 0; k0 < K; k0 += 32) {
    gload16(Ag0 + k0, As0);
    gload16(Ag1 + k0, As0 + 2048);
    gload16(Bg0 + k0, Bs0);
    gload16(Bg1 + k0, Bs0 + 2048);
    __syncthreads();
    short8 af[4], bfr[4];
#pragma unroll
    for (int t = 0; t < 4; ++t) {
      af[t]  = *(const short8*)&As[(wr * 64 + t * 16 + m15) * 32 + q8];
      bfr[t] = *(const short8*)&Bs[(wc * 64 + t * 16 + m15) * 32 + q8];
    }
#pragma unroll
    for (int mt = 0; mt < 4; ++mt)
#pragma unroll
      for (int nt = 0; nt < 4; ++nt)
        acc[mt][nt] = __builtin_amdgcn_mfma_f32_16x16x32_bf16(af[mt], bfr[nt], acc[mt][nt], 0, 0, 0);
    __syncthreads();   // all waves done reading As/Bs -> safe to overlay beta
  }

  // --- softmax over dk per row (4 regs + shfl_xor across the 16-lane group) ---
#pragma unroll
  for (int mt = 0; mt < 4; ++mt) {
#pragma unroll
    for (int i = 0; i < 4; ++i) {
      float mx = fmaxf(fmaxf(acc[mt][0][i], acc[mt][1][i]),
                       fmaxf(acc[mt][2][i], acc[mt][3][i]));
#pragma unroll
      for (int s = 1; s < 16; s <<= 1) mx = fmaxf(mx, __shfl_xor(mx, s));
      float e[4], sum = 0.f;
#pragma unroll
      for (int nt = 0; nt < 4; ++nt) { e[nt] = __expf(acc[mt][nt][i] - mx); sum += e[nt]; }
#pragma unroll
      for (int s = 1; s < 16; s <<= 1) sum += __shfl_xor(sum, s);
      const float inv = 1.f / sum;
      const int r = wr * 64 + mt * 16 + q4 + i;
#pragma unroll
      for (int nt = 0; nt < 4; ++nt)
        beta_s[r * 136 + wc * 64 + nt * 16 + m15] = f2b(e[nt] * inv);
    }
  }
  __syncthreads();

  // --- z = beta @ kv (kv hi/lo from L2-resident kvT, straight to registers) ---
  const int hb = (int)(bcol >> 6) + wc;        // head 0..15
  const int bb = (int)(brow >> 12);            // batch 0..3
  const long kvbase = ((long)(bb * 16 + hb)) << 12;

  float4v zacc[4][4];
#pragma unroll
  for (int i = 0; i < 4; ++i)
#pragma unroll
    for (int j = 0; j < 4; ++j) zacc[i][j] = (float4v){0.f, 0.f, 0.f, 0.f};

#pragma unroll
  for (int nt = 0; nt < 4; ++nt) {
    short8 bh2[2], bl2[2];
#pragma unroll
    for (int kk = 0; kk < 2; ++kk) {
      const float* kp = kvT + kvbase + (nt * 16 + m15) * 64 + kk * 32 + q8;
      float4v k0v = *(const float4v*)kp;
      float4v k1v = *(const float4v*)(kp + 4);
      unsigned short hh[8], ll[8];
#pragma unroll
      for (int j = 0; j < 4; ++j) { split1(k0v[j], hh[j], ll[j]); split1(k1v[j], hh[4 + j], ll[4 + j]); }
#pragma unroll
      for (int j = 0; j < 8; ++j) { bh2[kk][j] = (short)hh[j]; bl2[kk][j] = (short)ll[j]; }
    }
#pragma unroll
    for (int mt = 0; mt < 4; ++mt) {
#pragma unroll
      for (int kk = 0; kk < 2; ++kk) {
        const short8 af = *(const short8*)&beta_s[(wr * 64 + mt * 16 + m15) * 136 + wc * 64 + kk * 32 + q8];
        zacc[mt][nt] = __builtin_amdgcn_mfma_f32_16x16x32_bf16(af, bh2[kk], zacc[mt][nt], 0, 0, 0);
        zacc[mt][nt] = __builtin_amdgcn_mfma_f32_16x16x32_bf16(af, bl2[kk], zacc[mt][nt], 0, 0, 0);
      }
    }
  }

  // --- write y: row = brow + wr*64 + mt*16 + q4 + i, col = hb*64 + nt*16 + m15 ---
#pragma unroll
  for (int mt = 0; mt < 4; ++mt)
#pragma unroll
    for (int nt = 0; nt < 4; ++nt)
#pragma unroll
      for (int i = 0; i < 4; ++i)
        y[(brow + wr * 64 + mt * 16 + q4 + i) * (long)DMODEL + hb * 64 + nt * 16 + m15] =
            f2b(zacc[mt][nt][i]);
}

extern "C" void kernel_launch(void* const* d_in, const int* in_sizes, int n_in,
                              void* d_out, int out_size, void* d_ws, size_t ws_size,
                              hipStream_t stream) {
  const float* Q  = (const float*)d_in[0];
  const float* Kk = (const float*)d_in[1];
  const float* V  = (const float*)d_in[2];
  const float* WQ = (const float*)d_in[3];
  const float* WK = (const float*)d_in[4];
  const float* WV = (const float*)d_in[5];
  const float* WO = (const float*)d_in[6];
  const float* MK = (const float*)d_in[7];
  const float* MV = (const float*)d_in[8];

  char* ws = (char*)d_ws;
  // Region plan (time-multiplexed; max offset ~153 MiB):
  //  R1 [0,32M):    Kh -> Vh -> pkv(25.2M f32)
  //  R2 [32M,64M):  Kl -> vb -> yb
  //  Eh [64M,96M):  Eh -> Qh
  //  El [96M,128M): El
  //  WB [128M,144M): weight hi/lo splits (hi/lo pairs at 4MB stride)
  //  S  [144M,...):  pZ / kvT
  //  d_out is written only by the final gemm.
  unsigned short* R1 = (unsigned short*)(ws);
  unsigned short* R2 = (unsigned short*)(ws + 33554432);
  unsigned short* Eh = (unsigned short*)(ws + 67108864);
  unsigned short* El = (unsigned short*)(ws + 100663296);
  const long WB = 134217728;
  unsigned short* Wbase = (unsigned short*)(ws + WB);
  unsigned short* WQh = Wbase;
  unsigned short* WKh = (unsigned short*)(ws + WB + 4194304);
  unsigned short* WVh = (unsigned short*)(ws + WB + 8388608);
  unsigned short* WOh = (unsigned short*)(ws + WB + 12582912);
  const long S = 150994944;
  float* pZ  = (float*)(ws + S);               // 64*24*64*4 = 393 KB
  float* kvT = (float*)(ws + S + 8683520);     // 1 MB
  float* pkv = (float*)R1;                     // 64*24*4096*4 = 25.2 MB
  unsigned short* Qh = Eh;                     // Qh overlays Eh (dead after kv_chunk)

  const dim3 blk(256);
  const int N = 1024, K = 1024;
  const int NELEM = 4 * NSEQ * DMODEL;   // 16.7M per input tensor

  // merged: K input hi/lo split + all four weight splits (one launch)
  cvt_kw<<<10240, blk, 0, stream>>>(Kk, R1, R2, WQ, WK, WV, WO, Wbase);

  // K projection + fused exp: 2-term GEMM -> Eh/El (bf16 split of exp(k*SCALE))
  gemm_2t_exp<<<1024, blk, 0, stream>>>(R1, R2, WKh, Eh, El, N, K);

  // V projection: hi-only bf16 in R1 (Kh dead), GEMM -> vb in R2 (Kl dead)
  cvt_hi<<<8192, blk, 0, stream>>>(V, R1, NELEM);
  gemm_bt<1><<<1024, blk, 0, stream>>>(R1, WVh, (void*)R2, N, K);

  // fused kv: per-chunk E^T@V via MFMA; pkv in R1 (Vh dead)
  kv_chunk<<<dim3(64, NCH), blk, 0, stream>>>(Eh, El, R2, MK, MV, pkv, pZ);

  // merged: Q -> bf16 hi into Eh region (Eh dead) + reduce_kv2 -> kvT
  cvt_q_reduce<<<9216, blk, 0, stream>>>(Q, Qh, pkv, pZ, kvT);

  // Q projection + beta softmax + z, fused: yb in R2 (vb dead)
  gemm_q_beta<<<1024, blk, 0, stream>>>(Qh, WQh, kvT, R2);

  // output projection -> d_out (single writer of d_out)
  gemm_bt<0><<<1024, blk, 0, stream>>>(R2, WOh, (float*)d_out, N, K);
}